// Round 14
// baseline (91.640 us; speedup 1.0000x reference)
//
#include <hip/hip_runtime.h>

// Problem constants (B=2, T=2048, D=1024, N_EXP=8, TOP_K=2, CAP_FACTOR=1.25)
#define N_TOK   4096
#define DDIM    1024
#define N_EXP   8
#define CAP     1280                       // floor(2*1.25*4096/8), even, >=4
#define ROW     (N_EXP * CAP)              // 10240 floats per token row
#define CB_ELEMS (N_TOK * ROW)             // 41,943,040 floats per output tensor

typedef __attribute__((ext_vector_type(4))) float f32x4;

// ws layout:
//   [0,     4096)  : uint  pk[1024]   packed 4-bit expert ids, entry-major:
//                    entry i = k*4096 + t -> nibble (i&7) of word (i>>3)
//   [4096,  20480) : f32   p0[4096]   softmax weight, slot k=0
//   [20480, 36864) : f32   p1[4096]   softmax weight, slot k=1

// ---------------------------------------------------------------------------
// Kernel 1: router — 4096x8 GEMV, top-2, softmax over the 2 selected logits.
// One wave per token (4/block); packed nibble output. (R9-proven, unchanged)
// ---------------------------------------------------------------------------
__global__ __launch_bounds__(256) void router_kernel(
    const float* __restrict__ x, const float* __restrict__ wg,
    unsigned int* __restrict__ pk,
    float* __restrict__ p0, float* __restrict__ p1)
{
    __shared__ int se0[4], se1[4];
    const int wave = threadIdx.x >> 6;
    const int lane = threadIdx.x & 63;
    const int t = blockIdx.x * 4 + wave;

    const float4* xt  = (const float4*)(x + (size_t)t * DDIM);  // 256 float4
    const float4* wg4 = (const float4*)wg;                      // [8][256]

    float acc[N_EXP];
#pragma unroll
    for (int e = 0; e < N_EXP; ++e) acc[e] = 0.f;

#pragma unroll
    for (int it = 0; it < 4; ++it) {
        const int d4 = lane + it * 64;
        const float4 xv = xt[d4];
#pragma unroll
        for (int e = 0; e < N_EXP; ++e) {
            const float4 wv = wg4[e * 256 + d4];
            acc[e] = fmaf(xv.x, wv.x,
                     fmaf(xv.y, wv.y,
                     fmaf(xv.z, wv.z,
                     fmaf(xv.w, wv.w, acc[e]))));
        }
    }

#pragma unroll
    for (int e = 0; e < N_EXP; ++e) {
#pragma unroll
        for (int off = 32; off >= 1; off >>= 1)
            acc[e] += __shfl_xor(acc[e], off, 64);
    }

    if (lane == 0) {
        // stable top-2 (strict >) matches jax.lax.top_k tie-breaking
        float v0 = -3.402823466e38f, v1 = -3.402823466e38f;
        int   i0 = 0, i1 = 0;
#pragma unroll
        for (int e = 0; e < N_EXP; ++e) {
            const float v = acc[e];
            if (v > v0)      { v1 = v0; i1 = i0; v0 = v; i0 = e; }
            else if (v > v1) { v1 = v;  i1 = e; }
        }
        const float ex  = expf(v1 - v0);
        const float inv = 1.f / (1.f + ex);
        p0[t] = inv;        // softmax([v0,v1])[0]
        p1[t] = ex * inv;   // softmax([v0,v1])[1]
        se0[wave] = i0;
        se1[wave] = i1;
    }
    __syncthreads();

    if (threadIdx.x == 0) {
        const int b = blockIdx.x;
        unsigned short* pks = (unsigned short*)pk;
        const unsigned short h0 = (unsigned short)(se0[0] | (se0[1] << 4) |
                                                   (se0[2] << 8) | (se0[3] << 12));
        const unsigned short h1 = (unsigned short)(se1[0] | (se1[1] << 4) |
                                                   (se1[2] << 8) | (se1[3] << 12));
        pks[b]        = h0;   // k=0 entries 4b..4b+3
        pks[1024 + b] = h1;   // k=1 entries 4096+4b..4096+4b+3
    }
}

// ---------------------------------------------------------------------------
// Kernel 2: fill — R9 structure EXACTLY, except the bulk zero stores are
// NONTEMPORAL (nt = no-allocate). d_out is 335.5 MB ~ 1.3x the 256 MB L3:
// regular stores write-allocate and evict dirty lines every time (the ~5.1
// TB/s wall every R3-R13 variant hit); nt streams past L3 to HBM (the 7 TB/s
// path the 1.34 GB d_ws fill takes). Fixups stay regular (barrier-ordered).
// Blocks [0,2048): cb rows of token pair; [2048,4096): mask rows.
// ---------------------------------------------------------------------------
__global__ __launch_bounds__(256) void fill_kernel(
    const unsigned int* __restrict__ pk, const float* __restrict__ p0,
    const float* __restrict__ p1, float* __restrict__ out)
{
    __shared__ unsigned int spk[1024];   // 4 KB packed expert ids
    __shared__ int s_e[4], s_r[4];

    const int  b     = blockIdx.x;
    const bool is_cb = (b < 2048);
    const int  t0    = (is_cb ? b : (b - 2048)) * 2;   // token pair base

    float* base = out + 8 + (is_cb ? 0 : (size_t)CB_ELEMS) + (size_t)t0 * ROW;
    f32x4* b4   = (f32x4*)base;                  // 5120 f32x4 = 80 KB contiguous
    const f32x4 z = {0.f, 0.f, 0.f, 0.f};

    // issue the zero stores first (NT: bypass L3 write-allocate)
#pragma unroll
    for (int it = 0; it < 20; ++it)
        __builtin_nontemporal_store(z, &b4[threadIdx.x + it * 256]);

#pragma unroll
    for (int j = 0; j < 4; ++j)
        spk[threadIdx.x + j * 256] = pk[threadIdx.x + j * 256];
    __syncthreads();                             // spk visible; stores drained

    const int wave = threadIdx.x >> 6;
    const int lane = threadIdx.x & 63;

    // wave w -> entry (token t0+(w>>1), slot w&1); rank = # prior same-e entries
    const int tt = t0 + (wave >> 1);
    const int i  = (wave & 1) * N_TOK + tt;
    const int e  = (spk[i >> 3] >> ((i & 7) * 4)) & 0xF;

    int cnt = 0;
    for (int j = 0; j < 16; ++j) {
        const unsigned int w  = spk[lane + j * 64];   // stride-64: 2-way bank, free
        const int          bi = (lane + j * 64) * 8;  // entry index of nibble 0
#pragma unroll
        for (int s = 0; s < 8; ++s)
            cnt += (bi + s < i && (int)((w >> (4 * s)) & 0xF) == e) ? 1 : 0;
    }
#pragma unroll
    for (int off = 32; off >= 1; off >>= 1)
        cnt += __shfl_xor(cnt, off, 64);

    if (lane == 0) { s_e[wave] = e; s_r[wave] = cnt; }
    __syncthreads();                             // vmcnt(0): zeros done; ranks visible

    if (threadIdx.x < 4) {
        const int r = s_r[threadIdx.x];
        if (r < CAP) {                           // dropped tokens (rank>=cap) skipped
            const int   tt2 = t0 + (threadIdx.x >> 1);
            const float w   = (threadIdx.x & 1) ? p1[tt2] : p0[tt2];
            const float v   = is_cb ? w : ((w != 0.f) ? 1.f : 0.f);
            base[(size_t)(tt2 - t0) * ROW + s_e[threadIdx.x] * CAP + r] = v;
        }
    }

    // block 0: used_capacity[8] = min(total per expert, CAP)
    if (b == 0) {
        for (int ee = wave * 2; ee < wave * 2 + 2; ++ee) {
            int c = 0;
            for (int j = 0; j < 16; ++j) {
                const unsigned int w = spk[lane + j * 64];
#pragma unroll
                for (int s = 0; s < 8; ++s)
                    c += ((int)((w >> (4 * s)) & 0xF) == ee) ? 1 : 0;
            }
#pragma unroll
            for (int off = 32; off >= 1; off >>= 1)
                c += __shfl_xor(c, off, 64);
            if (lane == 0) out[ee] = (float)min(c, CAP);
        }
    }
}

// ---------------------------------------------------------------------------
extern "C" void kernel_launch(void* const* d_in, const int* in_sizes, int n_in,
                              void* d_out, int out_size, void* d_ws, size_t ws_size,
                              hipStream_t stream)
{
    const float* x  = (const float*)d_in[0];   // [2,2048,1024] f32
    const float* wg = (const float*)d_in[1];   // [8,1024] f32
    float* out = (float*)d_out;                // [8] used | cb | mask

    char*         ws = (char*)d_ws;
    unsigned int* pk = (unsigned int*)(ws);
    float*        p0 = (float*)(ws + 4096);
    float*        p1 = (float*)(ws + 20480);

    router_kernel<<<N_TOK / 4, 256, 0, stream>>>(x, wg, pk, p0, p1);
    fill_kernel<<<4096, 256, 0, stream>>>(pk, p0, p1, out);
}

// Round 15
// 79.836 us; speedup vs baseline: 1.1479x; 1.1479x over previous
//
#include <hip/hip_runtime.h>

// Problem constants (B=2, T=2048, D=1024, N_EXP=8, TOP_K=2, CAP_FACTOR=1.25)
#define N_TOK   4096
#define DDIM    1024
#define N_EXP   8
#define CAP     1280                       // floor(2*1.25*4096/8), even, >=4
#define ROW     (N_EXP * CAP)              // 10240 floats per token row
#define CB_ELEMS (N_TOK * ROW)             // 41,943,040 floats per output tensor
#define OUT_FLOATS (8 + 2 * (size_t)CB_ELEMS)   // 83,886,088

typedef __attribute__((ext_vector_type(4))) float f32x4;

// ws layout:
//   [0,     4096)  : uint  pk[1024]   packed 4-bit expert ids, entry-major:
//                    entry i = k*4096 + t -> nibble (i&7) of word (i>>3)
//   [4096,  20480) : f32   p0[4096]   softmax weight, slot k=0
//   [20480, 36864) : f32   p1[4096]   softmax weight, slot k=1

// ---------------------------------------------------------------------------
// Kernel 1: router — 4096x8 GEMV, top-2, softmax over the 2 selected logits.
// One wave per token (4/block); packed nibble output. (R9-proven, unchanged)
// ---------------------------------------------------------------------------
__global__ __launch_bounds__(256) void router_kernel(
    const float* __restrict__ x, const float* __restrict__ wg,
    unsigned int* __restrict__ pk,
    float* __restrict__ p0, float* __restrict__ p1)
{
    __shared__ int se0[4], se1[4];
    const int wave = threadIdx.x >> 6;
    const int lane = threadIdx.x & 63;
    const int t = blockIdx.x * 4 + wave;

    const float4* xt  = (const float4*)(x + (size_t)t * DDIM);  // 256 float4
    const float4* wg4 = (const float4*)wg;                      // [8][256]

    float acc[N_EXP];
#pragma unroll
    for (int e = 0; e < N_EXP; ++e) acc[e] = 0.f;

#pragma unroll
    for (int it = 0; it < 4; ++it) {
        const int d4 = lane + it * 64;
        const float4 xv = xt[d4];
#pragma unroll
        for (int e = 0; e < N_EXP; ++e) {
            const float4 wv = wg4[e * 256 + d4];
            acc[e] = fmaf(xv.x, wv.x,
                     fmaf(xv.y, wv.y,
                     fmaf(xv.z, wv.z,
                     fmaf(xv.w, wv.w, acc[e]))));
        }
    }

#pragma unroll
    for (int e = 0; e < N_EXP; ++e) {
#pragma unroll
        for (int off = 32; off >= 1; off >>= 1)
            acc[e] += __shfl_xor(acc[e], off, 64);
    }

    if (lane == 0) {
        // stable top-2 (strict >) matches jax.lax.top_k tie-breaking
        float v0 = -3.402823466e38f, v1 = -3.402823466e38f;
        int   i0 = 0, i1 = 0;
#pragma unroll
        for (int e = 0; e < N_EXP; ++e) {
            const float v = acc[e];
            if (v > v0)      { v1 = v0; i1 = i0; v0 = v; i0 = e; }
            else if (v > v1) { v1 = v;  i1 = e; }
        }
        const float ex  = expf(v1 - v0);
        const float inv = 1.f / (1.f + ex);
        p0[t] = inv;        // softmax([v0,v1])[0]
        p1[t] = ex * inv;   // softmax([v0,v1])[1]
        se0[wave] = i0;
        se1[wave] = i1;
    }
    __syncthreads();

    if (threadIdx.x == 0) {
        const int b = blockIdx.x;
        unsigned short* pks = (unsigned short*)pk;
        const unsigned short h0 = (unsigned short)(se0[0] | (se0[1] << 4) |
                                                   (se0[2] << 8) | (se0[3] << 12));
        const unsigned short h1 = (unsigned short)(se1[0] | (se1[1] << 4) |
                                                   (se1[2] << 8) | (se1[3] << 12));
        pks[b]        = h0;   // k=0 entries 4b..4b+3
        pks[1024 + b] = h1;   // k=1 entries 4096+4b..4096+4b+3
    }
}

// ---------------------------------------------------------------------------
// Kernel 2: fixup — 2048 blocks x 4 waves; wave w of block j owns k-major
// entry i = 4j + w. Rank via R9-proven nibble count from LDS-staged pk;
// <=2 scattered stores per entry (cb + mask). Block 0 adds used_capacity.
// Runs after the memset -> kernel-boundary ordering. (R13-proven)
// ---------------------------------------------------------------------------
__global__ __launch_bounds__(256) void fixup_kernel(
    const unsigned int* __restrict__ pk, const float* __restrict__ p0,
    const float* __restrict__ p1, float* __restrict__ out)
{
    __shared__ unsigned int spk[1024];   // 4 KB packed expert ids
#pragma unroll
    for (int j = 0; j < 4; ++j)
        spk[threadIdx.x + j * 256] = pk[threadIdx.x + j * 256];
    __syncthreads();

    const int wave = threadIdx.x >> 6;
    const int lane = threadIdx.x & 63;
    const int i    = blockIdx.x * 4 + wave;          // k-major entry, < 8192
    const int t    = i & (N_TOK - 1);
    const int k    = i >> 12;

    unsigned int w[16];
#pragma unroll
    for (int j = 0; j < 16; ++j) w[j] = spk[lane + j * 64];  // all 1024 words

    const int e = (int)((spk[i >> 3] >> ((i & 7) * 4)) & 0xF);
    int cnt = 0;
#pragma unroll
    for (int j = 0; j < 16; ++j) {
        const int bi = (lane + j * 64) * 8;          // entry idx of nibble 0
#pragma unroll
        for (int s = 0; s < 8; ++s)
            cnt += (bi + s < i && (int)((w[j] >> (4 * s)) & 0xF) == e) ? 1 : 0;
    }
#pragma unroll
    for (int off = 32; off >= 1; off >>= 1)
        cnt += __shfl_xor(cnt, off, 64);

    if (lane == 0 && cnt < CAP) {                    // dropped tokens skipped
        const float wv = k ? p1[t] : p0[t];
        float* cb = out + 8 + (size_t)t * ROW + (size_t)e * CAP + cnt;
        cb[0]        = wv;
        cb[CB_ELEMS] = (wv != 0.f) ? 1.f : 0.f;
    }

    // block 0: used_capacity[8] — wave handles experts 2*wave, 2*wave+1
    if (blockIdx.x == 0) {
#pragma unroll
        for (int q = 0; q < 2; ++q) {
            const int ee = wave * 2 + q;
            int c = 0;
#pragma unroll
            for (int j = 0; j < 16; ++j) {
#pragma unroll
                for (int s = 0; s < 8; ++s)
                    c += ((int)((w[j] >> (4 * s)) & 0xF) == ee) ? 1 : 0;
            }
#pragma unroll
            for (int off = 32; off >= 1; off >>= 1)
                c += __shfl_xor(c, off, 64);
            if (lane == 0) out[ee] = (float)min(c, CAP);
        }
    }
}

// ---------------------------------------------------------------------------
extern "C" void kernel_launch(void* const* d_in, const int* in_sizes, int n_in,
                              void* d_out, int out_size, void* d_ws, size_t ws_size,
                              hipStream_t stream)
{
    const float* x  = (const float*)d_in[0];   // [2,2048,1024] f32
    const float* wg = (const float*)d_in[1];   // [8,1024] f32
    float* out = (float*)d_out;                // [8] used | cb | mask

    char*         ws = (char*)d_ws;
    unsigned int* pk = (unsigned int*)(ws);
    float*        p0 = (float*)(ws + 4096);
    float*        p1 = (float*)(ws + 20480);

    // Kernel 1: router (writes only workspace)
    router_kernel<<<N_TOK / 4, 256, 0, stream>>>(x, wg, pk, p0, p1);

    // Bulk zero of the WHOLE output via the runtime's own fill kernel
    // (the 7.0 TB/s fillBufferAligned path). Async + on-stream -> capturable.
    hipMemsetAsync(d_out, 0, OUT_FLOATS * sizeof(float), stream);

    // Kernel 2: scatter the ~8192 nonzeros + used_capacity header
    fixup_kernel<<<2048, 256, 0, stream>>>(pk, p0, p1, out);
}